// Round 8
// baseline (145.499 us; speedup 1.0000x reference)
//
#include <hip/hip_runtime.h>
#include <hip/hip_bf16.h>

typedef __attribute__((ext_vector_type(8))) short short8;
typedef __attribute__((ext_vector_type(4))) float f32x4;
typedef unsigned short ushort_t;
typedef unsigned int uint_t;

// Fixed problem dims
static constexpr int B  = 8;
static constexpr int CX = 64;
static constexpr int SX = 8192;   // 128*64
static constexpr int CY = 256;
static constexpr int SY = 2048;   // 64*32
static constexpr int D  = 32;     // Cy/8

// workspace layout (byte offsets)
static constexpr size_t OFF_Q  = 0;                          // bf16 [B][SY][D]   1 MB
static constexpr size_t OFF_K  = OFF_Q + (size_t)B*SY*D*2;   // bf16 [B][SY][D]   1 MB
static constexpr size_t OFF_V  = OFF_K + (size_t)B*SY*D*2;   // bf16 [B][CX][SY]  2 MB (c-major!)
static constexpr size_t OFF_O  = OFF_V + (size_t)B*CX*SY*2;  // f32  [B][CX][SY]  4 MB
static constexpr size_t OFF_P1 = OFF_O + (size_t)B*CX*SY*4;  // f32  [512][64]
static constexpr size_t OFF_P2 = OFF_P1 + 512*64*4;          // f32  [512][64]
static constexpr size_t OFF_SC = OFF_P2 + 512*64*4;          // f32  [64]
static constexpr size_t OFF_SH = OFF_SC + 64*4;              // f32  [64]

__device__ inline ushort_t f2bf(float f) {                   // RNE f32->bf16
    uint_t u = __builtin_bit_cast(uint_t, f);
    u += 0x7fffu + ((u >> 16) & 1u);
    return (ushort_t)(u >> 16);
}
__device__ inline uint_t pack_bf16(float a, float b) {       // (lo=a, hi=b)
    uint_t ua = __builtin_bit_cast(uint_t, a);
    uint_t ub = __builtin_bit_cast(uint_t, b);
    ua += 0x7fffu + ((ua >> 16) & 1u);
    ub += 0x7fffu + ((ub >> 16) & 1u);
    return (ua >> 16) | (ub & 0xffff0000u);
}

// ---------------------------------------------------------------------------
// K1: q/k 1x1 conv -> bf16 qT/kT [b][s][32]. (unchanged)
// ---------------------------------------------------------------------------
__global__ __launch_bounds__(1024) void k_qk(
    const float* __restrict__ y, const float* __restrict__ wq,
    const float* __restrict__ bq, const float* __restrict__ wk,
    const float* __restrict__ bk, ushort_t* __restrict__ qT, ushort_t* __restrict__ kT)
{
    __shared__ __align__(16) float ylds[256][68];
    __shared__ __align__(16) float wlds[256][68];
    const int t  = threadIdx.x;
    const int b  = blockIdx.x >> 5;
    const int s0 = (blockIdx.x & 31) << 6;

    {
        const int c  = t & 255;
        const int rb = (t >> 8) << 4;
#pragma unroll
        for (int i = 0; i < 16; ++i) {
            const int r = rb + i;
            wlds[c][r] = (r < 32) ? wq[r * CY + c] : wk[(r - 32) * CY + c];
        }
    }
    {
        const float4* y4 = reinterpret_cast<const float4*>(y);
#pragma unroll
        for (int p = 0; p < 4; ++p) {
            const int flat = p * 1024 + t;
            const int cc = flat >> 4, s4 = flat & 15;
            const float4 v = y4[(size_t)(b * CY + cc) * (SY / 4) + (s0 >> 2) + s4];
            *reinterpret_cast<float4*>(&ylds[cc][s4 * 4]) = v;
        }
    }
    __syncthreads();

    const int w = t >> 6, s = t & 63;
    float a0 = 0.f, a1 = 0.f, a2 = 0.f, a3 = 0.f;
#pragma unroll 4
    for (int c = 0; c < 256; ++c) {
        const float yv = ylds[c][s];
        const float4 wv = *reinterpret_cast<const float4*>(&wlds[c][w * 4]);
        a0 += wv.x * yv; a1 += wv.y * yv; a2 += wv.z * yv; a3 += wv.w * yv;
    }
    const int o = w * 4;
    float b0, b1, b2, b3;
    if (o < 32) { b0 = bq[o]; b1 = bq[o+1]; b2 = bq[o+2]; b3 = bq[o+3]; }
    else        { b0 = bk[o-32]; b1 = bk[o-31]; b2 = bk[o-30]; b3 = bk[o-29]; }

    __syncthreads();
    ushort_t* qlds = reinterpret_cast<ushort_t*>(&ylds[0][0]);  // [64 s][72 o-pad]
    {
        uint_t* q32 = reinterpret_cast<uint_t*>(qlds);
        const int base = s * 36 + (o >> 1);
        q32[base]     = pack_bf16(a0 + b0, a1 + b1);
        q32[base + 1] = pack_bf16(a2 + b2, a3 + b3);
    }
    __syncthreads();

    if (t < 512) {
        const int half = t >> 8;
        const int tt = t & 255;
        const int ss = tt >> 2, ch = tt & 3;
        const float4 vv = *reinterpret_cast<const float4*>(&qlds[ss * 72 + half * 32 + ch * 8]);
        ushort_t* dst = half == 0 ? qT : kT;
        reinterpret_cast<float4*>(dst)[(size_t)(b * SY + s0 + ss) * 4 + ch] = vv;
    }
}

// ---------------------------------------------------------------------------
// K2: pooled v -> bf16 vB [b][c][j] (c-major). (unchanged)
// ---------------------------------------------------------------------------
__global__ __launch_bounds__(1024) void k_v(
    const float* __restrict__ x, const float* __restrict__ wv,
    const float* __restrict__ bv, ushort_t* __restrict__ vB)
{
    __shared__ __align__(16) float xp[64][68];
    __shared__ __align__(16) float wt[64][68];
    const int t   = threadIdx.x;
    const int b   = blockIdx.x >> 5;
    const int jj0 = (blockIdx.x & 31) << 6;

#pragma unroll
    for (int p = 0; p < 4; ++p) {
        const int f = p * 1024 + t;
        const int co = f >> 6, ci = f & 63;
        wt[ci][co] = wv[co * 64 + ci];
    }
    {
        const float4* x4 = reinterpret_cast<const float4*>(x);
#pragma unroll
        for (int p = 0; p < 4; ++p) {
            const int f = p * 1024 + t;
            const int ci = f >> 6, j = f & 63;
            const float4 v = x4[(size_t)(b * CX + ci) * (SX / 4) + jj0 + j];
            xp[ci][j] = (v.x + v.y) + (v.z + v.w);
        }
    }
    __syncthreads();

    const int w = t >> 6, j = t & 63;
    float a0 = 0.f, a1 = 0.f, a2 = 0.f, a3 = 0.f;
#pragma unroll 4
    for (int ci = 0; ci < 64; ++ci) {
        const float xv = xp[ci][j];
        const float4 w4 = *reinterpret_cast<const float4*>(&wt[ci][w * 4]);
        a0 += w4.x * xv; a1 += w4.y * xv; a2 += w4.z * xv; a3 += w4.w * xv;
    }
    const int c0 = w * 4;
    const size_t base = (size_t)(b * CX) * SY + jj0 + j;
    vB[base + (size_t)(c0 + 0) * SY] = f2bf(a0 + 4.f * bv[c0 + 0]);
    vB[base + (size_t)(c0 + 1) * SY] = f2bf(a1 + 4.f * bv[c0 + 1]);
    vB[base + (size_t)(c0 + 2) * SY] = f2bf(a2 + 4.f * bv[c0 + 2]);
    vB[base + (size_t)(c0 + 3) * SY] = f2bf(a3 + 4.f * bv[c0 + 3]);
}

// ---------------------------------------------------------------------------
// K3 v4: lockstep chunked MFMA flash attention, 2 blocks/CU.
// grid 512 (b x 64 slabs of 32 i-rows), block 1024 = 16 waves.
// LDS 56KB: K dbuf 2x8KB | V dbuf 2x16KB | P 8KB -> 2 blocks/CU so one
// block's compute hides the other's staging drain + barriers.
// QK role: wave=(jtt=w>>1, m=w&1): 1 kf read, 1 mfma, 4 exps, 1 P uint2.
// PV role: wave=(n=w&3, ks=w>>2): 1 vf + 2 pf reads, 2 mfmas (m=0,1).
// Epilogue: 4-round ks-merge into Otile[64][40], invL[32], BN partials,
// coalesced O write.
// ---------------------------------------------------------------------------
__global__ __launch_bounds__(1024) void k_attn(
    const ushort_t* __restrict__ qT, const ushort_t* __restrict__ kT,
    const ushort_t* __restrict__ vB, float* __restrict__ O,
    float* __restrict__ part1, float* __restrict__ part2)
{
    __shared__ __align__(16) unsigned char smem[57344];
    unsigned char* Kb0 = smem;            // [128 j][32 d] bf16 = 8KB
    unsigned char* Kb1 = smem + 8192;
    unsigned char* Vb0 = smem + 16384;    // [64 c][128 j] bf16, swizzled = 16KB
    unsigned char* Vb1 = smem + 32768;
    unsigned char* Pl  = smem + 49152;    // [32 i][128 j] bf16, rows 256B, XOR-swz
    // epilogue overlay (post-loop, barrier-separated)
    float* Otile = reinterpret_cast<float*>(smem);           // [64 c][40 pad] f32
    float* Lpart = reinterpret_cast<float*>(smem + 10240);   // [8 jtt][32 i]
    float* invL  = reinterpret_cast<float*>(smem + 11264);   // [32 i]

    const int t  = threadIdx.x;
    const int w  = t >> 6, l = t & 63;
    const int g  = l >> 4, li = l & 15;
    const int b  = blockIdx.x >> 6;
    const int i0 = (blockIdx.x & 63) << 5;

    const int jtt = w >> 1, m = w & 1;     // QK role
    const int n   = w & 3,  ks = w >> 2;   // PV role

    const ushort_t* kb = kT + (size_t)b * SY * D;
    const ushort_t* vb = vB + (size_t)b * CX * SY;

    // Q B-fragment for this wave's i-tile
    const short8 qf = *reinterpret_cast<const short8*>(
        qT + ((size_t)(b * SY + i0 + m * 16 + li)) * D + g * 8);

    const int koff = w * 1024 + l * 16;                 // waves 0..7: K flat slice
    const int vc = w * 4 + g;                           // V: c-row
    const int vldso = vc * 256 + li * 16;               // V LDS offset (linear)
    const unsigned char* kgb = reinterpret_cast<const unsigned char*>(kb);
    const unsigned char* vgb = reinterpret_cast<const unsigned char*>(vb)
                             + (size_t)vc * (SY * 2) + ((li ^ (vc & 7)) * 16);

    f32x4 acc0 = (f32x4){0.f, 0.f, 0.f, 0.f};
    f32x4 acc1 = (f32x4){0.f, 0.f, 0.f, 0.f};
    float lsum = 0.f;
    const int swzP = (li & 7) << 4;

    // prologue: stage chunk 0 into buf0
    {
        short8 kr, vr;
        if (w < 8) kr = *reinterpret_cast<const short8*>(kgb + koff);
        vr = *reinterpret_cast<const short8*>(vgb);
        if (w < 8) *reinterpret_cast<short8*>(Kb0 + koff) = kr;
        *reinterpret_cast<short8*>(Vb0 + vldso) = vr;
    }
    __syncthreads();

    for (int ch = 0; ch < 16; ++ch) {
        unsigned char* Kc = (ch & 1) ? Kb1 : Kb0;
        unsigned char* Vc = (ch & 1) ? Vb1 : Vb0;
        unsigned char* Kn = (ch & 1) ? Kb0 : Kb1;
        unsigned char* Vn = (ch & 1) ? Vb0 : Vb1;

        // issue next-chunk global loads early (latency hides under compute)
        short8 kr, vr;
        if (ch < 15) {
            if (w < 8) kr = *reinterpret_cast<const short8*>(kgb + (size_t)(ch + 1) * 8192 + koff);
            vr = *reinterpret_cast<const short8*>(vgb + (size_t)(ch + 1) * 256);
        }

        // --- QK: one kf, one mfma ---
        const short8 kf = *reinterpret_cast<const short8*>(Kc + (jtt * 16 + li) * 64 + g * 16);
        const f32x4 d0 = __builtin_amdgcn_mfma_f32_16x16x32_bf16(kf, qf, (f32x4){0.f,0.f,0.f,0.f}, 0, 0, 0);

        // --- exp + pack + P write (row m*16+li, cols jtt*16+4g..+3) ---
        {
            const float e0 = __expf(d0[0]), e1 = __expf(d0[1]);
            const float e2 = __expf(d0[2]), e3 = __expf(d0[3]);
            lsum += (e0 + e1) + (e2 + e3);
            uint2 pw; pw.x = pack_bf16(e0, e1); pw.y = pack_bf16(e2, e3);
            *reinterpret_cast<uint2*>(Pl + (m * 16 + li) * 256 + ((jtt * 32 + g * 8) ^ swzP)) = pw;
        }
        __syncthreads();   // P published

        // --- PV: partial O(m=0,1, n; ks) ---
        const short8 vf = *reinterpret_cast<const short8*>(
            Vc + (n * 16 + li) * 256 + ((ks * 64 + g * 16) ^ swzP));
        const short8 pf0 = *reinterpret_cast<const short8*>(
            Pl + li * 256 + ((ks * 64 + g * 16) ^ swzP));
        acc0 = __builtin_amdgcn_mfma_f32_16x16x32_bf16(pf0, vf, acc0, 0, 0, 0);
        const short8 pf1 = *reinterpret_cast<const short8*>(
            Pl + (16 + li) * 256 + ((ks * 64 + g * 16) ^ swzP));
        acc1 = __builtin_amdgcn_mfma_f32_16x16x32_bf16(pf1, vf, acc1, 0, 0, 0);

        // write staged regs into next buffers
        if (ch < 15) {
            if (w < 8) *reinterpret_cast<short8*>(Kn + koff) = kr;
            *reinterpret_cast<short8*>(Vn + vldso) = vr;
        }
        __syncthreads();   // next buffers ready; P free for overwrite
    }

    // ---- epilogue ----
    lsum += __shfl_xor(lsum, 16, 64);
    lsum += __shfl_xor(lsum, 32, 64);
    if (l < 16) Lpart[jtt * 32 + m * 16 + l] = lsum;

    if (ks == 0) {
        *reinterpret_cast<float4*>(&Otile[(n * 16 + li) * 40 + g * 4]) =
            make_float4(acc0[0], acc0[1], acc0[2], acc0[3]);
        *reinterpret_cast<float4*>(&Otile[(n * 16 + li) * 40 + 16 + g * 4]) =
            make_float4(acc1[0], acc1[1], acc1[2], acc1[3]);
    }
    __syncthreads();
    if (t < 32) {
        float L = 0.f;
#pragma unroll
        for (int jj = 0; jj < 8; ++jj) L += Lpart[jj * 32 + t];
        invL[t] = 1.f / L;
    }
    if (ks == 1) {
        float4* p0 = reinterpret_cast<float4*>(&Otile[(n * 16 + li) * 40 + g * 4]);
        float4 v0 = *p0;
        v0.x += acc0[0]; v0.y += acc0[1]; v0.z += acc0[2]; v0.w += acc0[3];
        *p0 = v0;
        float4* p1 = reinterpret_cast<float4*>(&Otile[(n * 16 + li) * 40 + 16 + g * 4]);
        float4 v1 = *p1;
        v1.x += acc1[0]; v1.y += acc1[1]; v1.z += acc1[2]; v1.w += acc1[3];
        *p1 = v1;
    }
    __syncthreads();
    if (ks == 2) {
        float4* p0 = reinterpret_cast<float4*>(&Otile[(n * 16 + li) * 40 + g * 4]);
        float4 v0 = *p0;
        v0.x += acc0[0]; v0.y += acc0[1]; v0.z += acc0[2]; v0.w += acc0[3];
        *p0 = v0;
        float4* p1 = reinterpret_cast<float4*>(&Otile[(n * 16 + li) * 40 + 16 + g * 4]);
        float4 v1 = *p1;
        v1.x += acc1[0]; v1.y += acc1[1]; v1.z += acc1[2]; v1.w += acc1[3];
        *p1 = v1;
    }
    __syncthreads();
    if (ks == 3) {
        float4* p0 = reinterpret_cast<float4*>(&Otile[(n * 16 + li) * 40 + g * 4]);
        float4 v0 = *p0;
        v0.x += acc0[0]; v0.y += acc0[1]; v0.z += acc0[2]; v0.w += acc0[3];
        *p0 = v0;
        float4* p1 = reinterpret_cast<float4*>(&Otile[(n * 16 + li) * 40 + 16 + g * 4]);
        float4 v1 = *p1;
        v1.x += acc1[0]; v1.y += acc1[1]; v1.z += acc1[2]; v1.w += acc1[3];
        *p1 = v1;
    }
    __syncthreads();

    // BN partial sums over this block's 32 i-rows (normalized O, pre-gamma)
    if (t < 64) {
        float sa = 0.f, sq = 0.f;
        for (int i = 0; i < 32; ++i) {
            const float v = Otile[t * 40 + i] * invL[i];
            sa += v; sq += v * v;
        }
        part1[blockIdx.x * 64 + t] = sa;
        part2[blockIdx.x * 64 + t] = sq;
    }

    // coalesced transposed write: O[b][c][i0..i0+31]
    if (t < 512) {
        const int c = t >> 3, i4 = t & 7;
        float4 o;
        o.x = Otile[c * 40 + i4 * 4 + 0] * invL[i4 * 4 + 0];
        o.y = Otile[c * 40 + i4 * 4 + 1] * invL[i4 * 4 + 1];
        o.z = Otile[c * 40 + i4 * 4 + 2] * invL[i4 * 4 + 2];
        o.w = Otile[c * 40 + i4 * 4 + 3] * invL[i4 * 4 + 3];
        reinterpret_cast<float4*>(O)[(size_t)(b * CX + c) * (SY / 4) + (i0 >> 2) + i4] = o;
    }
}

// ---------------------------------------------------------------------------
// K4: reduce 512-block BN partials -> per-channel scale/shift. block 1024.
// ---------------------------------------------------------------------------
__global__ __launch_bounds__(1024) void k_bn(
    const float* __restrict__ part1, const float* __restrict__ part2,
    const float* __restrict__ gamma, const float* __restrict__ bn_w,
    const float* __restrict__ bn_b, float* __restrict__ sc,
    float* __restrict__ sh)
{
    __shared__ float r1[16][64], r2[16][64];
    const int t = threadIdx.x;
    const int c = t & 63, q = t >> 6;
    float s1 = 0.f, s2 = 0.f;
#pragma unroll
    for (int n = 0; n < 32; ++n) {
        const int row = n * 16 + q;
        s1 += part1[row * 64 + c];
        s2 += part2[row * 64 + c];
    }
    r1[q][c] = s1; r2[q][c] = s2;
    __syncthreads();
    if (t < 64) {
        float S1 = 0.f, S2 = 0.f;
#pragma unroll
        for (int k = 0; k < 16; ++k) { S1 += r1[k][t]; S2 += r2[k][t]; }
        const float g = gamma[0];
        const float invN = 1.f / 16384.f;       // B*SY
        const float mean = S1 * invN;
        const float var  = S2 * invN - mean * mean;
        const float inv  = rsqrtf(g * g * var + 1e-5f);
        const float scale = g * inv * bn_w[t];
        sc[t] = scale;
        sh[t] = bn_b[t] - mean * scale;
    }
}

// ---------------------------------------------------------------------------
// K5: epilogue.  out[b][c][4jj..4jj+3] = x + O[b][c][jj]*scale[c] + shift[c]
// ---------------------------------------------------------------------------
__global__ __launch_bounds__(256) void k_out(
    const float* __restrict__ x, const float* __restrict__ Obuf,
    const float* __restrict__ sc, const float* __restrict__ sh,
    float* __restrict__ out)
{
    const int gid = blockIdx.x * 256 + threadIdx.x;   // 0 .. B*CX*SY-1
    const int c = (gid >> 11) & 63;
    const float o  = Obuf[gid];
    const float4 xv = reinterpret_cast<const float4*>(x)[gid];
    const float val = o * sc[c] + sh[c];
    float4 r;
    r.x = xv.x + val; r.y = xv.y + val; r.z = xv.z + val; r.w = xv.w + val;
    reinterpret_cast<float4*>(out)[gid] = r;
}

extern "C" void kernel_launch(void* const* d_in, const int* in_sizes, int n_in,
                              void* d_out, int out_size, void* d_ws, size_t ws_size,
                              hipStream_t stream)
{
    (void)in_sizes; (void)n_in; (void)out_size; (void)ws_size;
    const float* x  = (const float*)d_in[0];
    const float* y  = (const float*)d_in[1];
    const float* wq = (const float*)d_in[2];
    const float* bq = (const float*)d_in[3];
    const float* wk = (const float*)d_in[4];
    const float* bk = (const float*)d_in[5];
    const float* wv = (const float*)d_in[6];
    const float* bv = (const float*)d_in[7];
    const float* gm = (const float*)d_in[8];
    const float* bw = (const float*)d_in[9];
    const float* bb = (const float*)d_in[10];

    char* ws = (char*)d_ws;
    ushort_t* qT  = (ushort_t*)(ws + OFF_Q);
    ushort_t* kT  = (ushort_t*)(ws + OFF_K);
    ushort_t* vBp = (ushort_t*)(ws + OFF_V);
    float*    Ob  = (float*)(ws + OFF_O);
    float*    p1  = (float*)(ws + OFF_P1);
    float*    p2  = (float*)(ws + OFF_P2);
    float*    scp = (float*)(ws + OFF_SC);
    float*    shp = (float*)(ws + OFF_SH);

    k_qk  <<<256, 1024, 0, stream>>>(y, wq, bq, wk, bk, qT, kT);
    k_v   <<<256, 1024, 0, stream>>>(x, wv, bv, vBp);
    k_attn<<<512, 1024, 0, stream>>>(qT, kT, vBp, Ob, p1, p2);
    k_bn  <<<1,   1024, 0, stream>>>(p1, p2, gm, bw, bb, scp, shp);
    k_out <<<4096, 256, 0, stream>>>(x, Ob, scp, shp, (float*)d_out);
}

// Round 9
// 133.169 us; speedup vs baseline: 1.0926x; 1.0926x over previous
//
#include <hip/hip_runtime.h>
#include <hip/hip_bf16.h>

typedef __attribute__((ext_vector_type(8))) short short8;
typedef __attribute__((ext_vector_type(4))) float f32x4;
typedef unsigned short ushort_t;
typedef unsigned int uint_t;

// Fixed problem dims
static constexpr int B  = 8;
static constexpr int CX = 64;
static constexpr int SX = 8192;   // 128*64
static constexpr int CY = 256;
static constexpr int SY = 2048;   // 64*32
static constexpr int D  = 32;     // Cy/8

// workspace layout (byte offsets)
static constexpr size_t OFF_Q  = 0;                          // bf16 [B][SY][D]   1 MB
static constexpr size_t OFF_K  = OFF_Q + (size_t)B*SY*D*2;   // bf16 [B][SY][D]   1 MB
static constexpr size_t OFF_V  = OFF_K + (size_t)B*SY*D*2;   // bf16 [B][CX][SY]  2 MB (c-major!)
static constexpr size_t OFF_O  = OFF_V + (size_t)B*CX*SY*2;  // f32  [B][CX][SY]  4 MB
static constexpr size_t OFF_P1 = OFF_O + (size_t)B*CX*SY*4;  // f32  [256][64]
static constexpr size_t OFF_P2 = OFF_P1 + 512*64*4;          // f32  [256][64]
static constexpr size_t OFF_SC = OFF_P2 + 512*64*4;          // f32  [64]
static constexpr size_t OFF_SH = OFF_SC + 64*4;              // f32  [64]

__device__ inline ushort_t f2bf(float f) {                   // RNE f32->bf16
    uint_t u = __builtin_bit_cast(uint_t, f);
    u += 0x7fffu + ((u >> 16) & 1u);
    return (ushort_t)(u >> 16);
}
__device__ inline uint_t pack_bf16(float a, float b) {       // (lo=a, hi=b)
    uint_t ua = __builtin_bit_cast(uint_t, a);
    uint_t ub = __builtin_bit_cast(uint_t, b);
    ua += 0x7fffu + ((ua >> 16) & 1u);
    ub += 0x7fffu + ((ub >> 16) & 1u);
    return (ua >> 16) | (ub & 0xffff0000u);
}

// ---------------------------------------------------------------------------
// K1 v2: q/k 1x1 conv via MFMA -> bf16 qT/kT [b][s][32].
// grid 256 (b x 32 s-tiles of 64), block 1024 = 16 waves.
// Stage W [64o][256c] bf16 + y^T [64s][256c] bf16 in LDS (XOR-swizzled rows,
// same involution on write and read). Wave (ot,st) computes D[16o x 16s] via
// 8x mfma_16x16x32 over c. Epilogue: +bias, pack, uint2 global write.
// ---------------------------------------------------------------------------
__global__ __launch_bounds__(1024) void k_qk(
    const float* __restrict__ y, const float* __restrict__ wq,
    const float* __restrict__ bq, const float* __restrict__ wk,
    const float* __restrict__ bk, ushort_t* __restrict__ qT, ushort_t* __restrict__ kT)
{
    __shared__ __align__(16) unsigned char Wl[32768];   // [64 o][256 c] bf16, rows 512B, swz
    __shared__ __align__(16) unsigned char Yl[32768];   // [64 s][256 c] bf16, rows 512B, swz
    const int t  = threadIdx.x;
    const int b  = blockIdx.x >> 5;
    const int s0 = (blockIdx.x & 31) << 6;

    // stage W (o<32: wq, o>=32: wk), pack c-pairs, swizzled
#pragma unroll
    for (int p = 0; p < 8; ++p) {
        const int idx = p * 1024 + t;           // 0..8191
        const int o   = idx >> 7;               // 0..63
        const int c2  = idx & 127;              // c-pair index
        const float f0 = (o < 32) ? wq[o * CY + 2 * c2]     : wk[(o - 32) * CY + 2 * c2];
        const float f1 = (o < 32) ? wq[o * CY + 2 * c2 + 1] : wk[(o - 32) * CY + 2 * c2 + 1];
        *reinterpret_cast<uint_t*>(Wl + ((o * 512 + c2 * 4) ^ ((o & 7) << 4))) = pack_bf16(f0, f1);
    }
    // stage y^T: thread (cg = t>>6 -> 16 c's, l = t&63 -> s); coalesced 256B reads
    {
        const int l = t & 63, cg = t >> 6;
        const float* ysrc = y + (size_t)(b * CY + cg * 16) * SY + s0 + l;
#pragma unroll
        for (int k = 0; k < 8; ++k) {
            const float f0 = ysrc[(2 * k)     * SY];
            const float f1 = ysrc[(2 * k + 1) * SY];
            const int c = cg * 16 + 2 * k;
            *reinterpret_cast<uint_t*>(Yl + ((l * 512 + c * 2) ^ ((l & 7) << 4))) = pack_bf16(f0, f1);
        }
    }
    __syncthreads();

    const int w  = t >> 6, l = t & 63;
    const int li = l & 15, g = l >> 4;
    const int ot = w & 3,  st = w >> 2;
    const int oo = ot * 16 + li;                // A row (o)
    const int ss = st * 16 + li;                // B col (s)

    f32x4 acc = (f32x4){0.f, 0.f, 0.f, 0.f};
#pragma unroll
    for (int ch = 0; ch < 8; ++ch) {
        const short8 wf = *reinterpret_cast<const short8*>(
            Wl + ((oo * 512 + ch * 64 + g * 16) ^ ((oo & 7) << 4)));
        const short8 yf = *reinterpret_cast<const short8*>(
            Yl + ((ss * 512 + ch * 64 + g * 16) ^ ((ss & 7) << 4)));
        acc = __builtin_amdgcn_mfma_f32_16x16x32_bf16(wf, yf, acc, 0, 0, 0);
    }
    // lane holds D[o = ot*16 + g*4 + r][s = st*16 + li]
    const float* bias = (ot < 2) ? bq : bk;
    const int ob = (ot & 1) * 16 + g * 4;       // o within the 32-wide q (or k) dim
    const float v0 = acc[0] + bias[ob + 0];
    const float v1 = acc[1] + bias[ob + 1];
    const float v2 = acc[2] + bias[ob + 2];
    const float v3 = acc[3] + bias[ob + 3];
    uint2 pw; pw.x = pack_bf16(v0, v1); pw.y = pack_bf16(v2, v3);
    ushort_t* dst = (ot < 2) ? qT : kT;
    *reinterpret_cast<uint2*>(dst + (size_t)(b * SY + s0 + ss) * D + ob) = pw;
}

// ---------------------------------------------------------------------------
// K2: pooled v -> bf16 vB [b][c][j] (c-major). (unchanged)
// ---------------------------------------------------------------------------
__global__ __launch_bounds__(1024) void k_v(
    const float* __restrict__ x, const float* __restrict__ wv,
    const float* __restrict__ bv, ushort_t* __restrict__ vB)
{
    __shared__ __align__(16) float xp[64][68];
    __shared__ __align__(16) float wt[64][68];
    const int t   = threadIdx.x;
    const int b   = blockIdx.x >> 5;
    const int jj0 = (blockIdx.x & 31) << 6;

#pragma unroll
    for (int p = 0; p < 4; ++p) {
        const int f = p * 1024 + t;
        const int co = f >> 6, ci = f & 63;
        wt[ci][co] = wv[co * 64 + ci];
    }
    {
        const float4* x4 = reinterpret_cast<const float4*>(x);
#pragma unroll
        for (int p = 0; p < 4; ++p) {
            const int f = p * 1024 + t;
            const int ci = f >> 6, j = f & 63;
            const float4 v = x4[(size_t)(b * CX + ci) * (SX / 4) + jj0 + j];
            xp[ci][j] = (v.x + v.y) + (v.z + v.w);
        }
    }
    __syncthreads();

    const int w = t >> 6, j = t & 63;
    float a0 = 0.f, a1 = 0.f, a2 = 0.f, a3 = 0.f;
#pragma unroll 4
    for (int ci = 0; ci < 64; ++ci) {
        const float xv = xp[ci][j];
        const float4 w4 = *reinterpret_cast<const float4*>(&wt[ci][w * 4]);
        a0 += w4.x * xv; a1 += w4.y * xv; a2 += w4.z * xv; a3 += w4.w * xv;
    }
    const int c0 = w * 4;
    const size_t base = (size_t)(b * CX) * SY + jj0 + j;
    vB[base + (size_t)(c0 + 0) * SY] = f2bf(a0 + 4.f * bv[c0 + 0]);
    vB[base + (size_t)(c0 + 1) * SY] = f2bf(a1 + 4.f * bv[c0 + 1]);
    vB[base + (size_t)(c0 + 2) * SY] = f2bf(a2 + 4.f * bv[c0 + 2]);
    vB[base + (size_t)(c0 + 3) * SY] = f2bf(a3 + 4.f * bv[c0 + 3]);
}

// ---------------------------------------------------------------------------
// K3 v3 (reverted from R6 — best measured): lockstep chunked MFMA flash attn.
// grid 256 (b x 32 slabs of 64 i-rows), block 1024 = 16 waves.
// ---------------------------------------------------------------------------
__global__ __launch_bounds__(1024) void k_attn(
    const ushort_t* __restrict__ qT, const ushort_t* __restrict__ kT,
    const ushort_t* __restrict__ vB, float* __restrict__ O,
    float* __restrict__ part1, float* __restrict__ part2)
{
    __shared__ __align__(16) unsigned char smem[65536];
    unsigned char* Kb0 = smem;
    unsigned char* Kb1 = smem + 8192;
    unsigned char* Vb0 = smem + 16384;
    unsigned char* Vb1 = smem + 32768;
    unsigned char* Pl  = smem + 49152;
    float* Otile = reinterpret_cast<float*>(smem);
    float* Lpart = reinterpret_cast<float*>(smem + 17408);
    float* invL  = reinterpret_cast<float*>(smem + 19456);

    const int t  = threadIdx.x;
    const int w  = t >> 6, l = t & 63;
    const int g  = l >> 4, li = l & 15;
    const int b  = blockIdx.x >> 5;
    const int i0 = (blockIdx.x & 31) << 6;

    const int jtt = w >> 1, h = w & 1;     // QK role
    const int n   = w & 3,  ks = w >> 2;   // PV role
    const int m0  = 2 * h, m1 = 2 * h + 1;

    const ushort_t* kb = kT + (size_t)b * SY * D;
    const ushort_t* vb = vB + (size_t)b * CX * SY;

    const short8 qf0 = *reinterpret_cast<const short8*>(
        qT + ((size_t)(b * SY + i0 + m0 * 16 + li)) * D + g * 8);
    const short8 qf1 = *reinterpret_cast<const short8*>(
        qT + ((size_t)(b * SY + i0 + m1 * 16 + li)) * D + g * 8);

    const int koff = w * 1024 + l * 16;
    const int vc = w * 4 + g;
    const int vldso = vc * 256 + li * 16;
    const unsigned char* kgb = reinterpret_cast<const unsigned char*>(kb);
    const unsigned char* vgb = reinterpret_cast<const unsigned char*>(vb)
                             + (size_t)vc * (SY * 2) + ((li ^ (vc & 7)) * 16);

    f32x4 acc[4];
#pragma unroll
    for (int m = 0; m < 4; ++m) acc[m] = (f32x4){0.f, 0.f, 0.f, 0.f};
    float lsum0 = 0.f, lsum1 = 0.f;

    const int swzP = (li & 7) << 4;

    {
        short8 kr, vr;
        if (w < 8) kr = *reinterpret_cast<const short8*>(kgb + koff);
        vr = *reinterpret_cast<const short8*>(vgb);
        if (w < 8) *reinterpret_cast<short8*>(Kb0 + koff) = kr;
        *reinterpret_cast<short8*>(Vb0 + vldso) = vr;
    }
    __syncthreads();

    for (int ch = 0; ch < 16; ++ch) {
        unsigned char* Kc = (ch & 1) ? Kb1 : Kb0;
        unsigned char* Vc = (ch & 1) ? Vb1 : Vb0;
        unsigned char* Kn = (ch & 1) ? Kb0 : Kb1;
        unsigned char* Vn = (ch & 1) ? Vb0 : Vb1;

        short8 kr, vr;
        if (ch < 15) {
            if (w < 8) kr = *reinterpret_cast<const short8*>(kgb + (size_t)(ch + 1) * 8192 + koff);
            vr = *reinterpret_cast<const short8*>(vgb + (size_t)(ch + 1) * 256);
        }

        const short8 kf = *reinterpret_cast<const short8*>(Kc + (jtt * 16 + li) * 64 + g * 16);
        const f32x4 d0 = __builtin_amdgcn_mfma_f32_16x16x32_bf16(kf, qf0, (f32x4){0.f,0.f,0.f,0.f}, 0, 0, 0);
        const f32x4 d1 = __builtin_amdgcn_mfma_f32_16x16x32_bf16(kf, qf1, (f32x4){0.f,0.f,0.f,0.f}, 0, 0, 0);

        {
            const float e0 = __expf(d0[0]), e1 = __expf(d0[1]);
            const float e2 = __expf(d0[2]), e3 = __expf(d0[3]);
            lsum0 += (e0 + e1) + (e2 + e3);
            uint2 pw; pw.x = pack_bf16(e0, e1); pw.y = pack_bf16(e2, e3);
            *reinterpret_cast<uint2*>(Pl + (m0 * 16 + li) * 256 + ((jtt * 32 + g * 8) ^ swzP)) = pw;
        }
        {
            const float e0 = __expf(d1[0]), e1 = __expf(d1[1]);
            const float e2 = __expf(d1[2]), e3 = __expf(d1[3]);
            lsum1 += (e0 + e1) + (e2 + e3);
            uint2 pw; pw.x = pack_bf16(e0, e1); pw.y = pack_bf16(e2, e3);
            *reinterpret_cast<uint2*>(Pl + (m1 * 16 + li) * 256 + ((jtt * 32 + g * 8) ^ swzP)) = pw;
        }
        __syncthreads();   // P published

        const short8 vf = *reinterpret_cast<const short8*>(
            Vc + (n * 16 + li) * 256 + ((ks * 64 + g * 16) ^ swzP));
#pragma unroll
        for (int m = 0; m < 4; ++m) {
            const short8 pf = *reinterpret_cast<const short8*>(
                Pl + (m * 16 + li) * 256 + ((ks * 64 + g * 16) ^ swzP));
            acc[m] = __builtin_amdgcn_mfma_f32_16x16x32_bf16(pf, vf, acc[m], 0, 0, 0);
        }

        if (ch < 15) {
            if (w < 8) *reinterpret_cast<short8*>(Kn + koff) = kr;
            *reinterpret_cast<short8*>(Vn + vldso) = vr;
        }
        __syncthreads();
    }

    // ---- epilogue ----
    lsum0 += __shfl_xor(lsum0, 16, 64);
    lsum0 += __shfl_xor(lsum0, 32, 64);
    lsum1 += __shfl_xor(lsum1, 16, 64);
    lsum1 += __shfl_xor(lsum1, 32, 64);
    if (l < 16) {
        Lpart[jtt * 64 + m0 * 16 + l] = lsum0;
        Lpart[jtt * 64 + m1 * 16 + l] = lsum1;
    }
    if (ks == 0) {
#pragma unroll
        for (int m = 0; m < 4; ++m) {
            float4 v = make_float4(acc[m][0], acc[m][1], acc[m][2], acc[m][3]);
            *reinterpret_cast<float4*>(&Otile[(n * 16 + li) * 68 + m * 16 + g * 4]) = v;
        }
    }
    __syncthreads();
    if (t < 64) {
        float L = 0.f;
#pragma unroll
        for (int jj = 0; jj < 8; ++jj) L += Lpart[jj * 64 + t];
        invL[t] = 1.f / L;
    }
    if (ks == 1) {
#pragma unroll
        for (int m = 0; m < 4; ++m) {
            float4* p = reinterpret_cast<float4*>(&Otile[(n * 16 + li) * 68 + m * 16 + g * 4]);
            float4 v = *p;
            v.x += acc[m][0]; v.y += acc[m][1]; v.z += acc[m][2]; v.w += acc[m][3];
            *p = v;
        }
    }
    __syncthreads();
    if (ks == 2) {
#pragma unroll
        for (int m = 0; m < 4; ++m) {
            float4* p = reinterpret_cast<float4*>(&Otile[(n * 16 + li) * 68 + m * 16 + g * 4]);
            float4 v = *p;
            v.x += acc[m][0]; v.y += acc[m][1]; v.z += acc[m][2]; v.w += acc[m][3];
            *p = v;
        }
    }
    __syncthreads();
    if (ks == 3) {
#pragma unroll
        for (int m = 0; m < 4; ++m) {
            float4* p = reinterpret_cast<float4*>(&Otile[(n * 16 + li) * 68 + m * 16 + g * 4]);
            float4 v = *p;
            v.x += acc[m][0]; v.y += acc[m][1]; v.z += acc[m][2]; v.w += acc[m][3];
            *p = v;
        }
    }
    __syncthreads();

    if (t < 64) {
        float sa = 0.f, sq = 0.f;
        for (int i = 0; i < 64; ++i) {
            const float v = Otile[t * 68 + i] * invL[i];
            sa += v; sq += v * v;
        }
        part1[blockIdx.x * 64 + t] = sa;
        part2[blockIdx.x * 64 + t] = sq;
    }

    {
        const int c = t >> 4, i4 = t & 15;
        float4 o;
        o.x = Otile[c * 68 + i4 * 4 + 0] * invL[i4 * 4 + 0];
        o.y = Otile[c * 68 + i4 * 4 + 1] * invL[i4 * 4 + 1];
        o.z = Otile[c * 68 + i4 * 4 + 2] * invL[i4 * 4 + 2];
        o.w = Otile[c * 68 + i4 * 4 + 3] * invL[i4 * 4 + 3];
        reinterpret_cast<float4*>(O)[(size_t)(b * CX + c) * (SY / 4) + (i0 >> 2) + i4] = o;
    }
}

// ---------------------------------------------------------------------------
// K4: reduce 256-block BN partials -> per-channel scale/shift. block 1024.
// ---------------------------------------------------------------------------
__global__ __launch_bounds__(1024) void k_bn(
    const float* __restrict__ part1, const float* __restrict__ part2,
    const float* __restrict__ gamma, const float* __restrict__ bn_w,
    const float* __restrict__ bn_b, float* __restrict__ sc,
    float* __restrict__ sh)
{
    __shared__ float r1[16][64], r2[16][64];
    const int t = threadIdx.x;
    const int c = t & 63, q = t >> 6;
    float s1 = 0.f, s2 = 0.f;
#pragma unroll
    for (int n = 0; n < 16; ++n) {
        const int row = n * 16 + q;
        s1 += part1[row * 64 + c];
        s2 += part2[row * 64 + c];
    }
    r1[q][c] = s1; r2[q][c] = s2;
    __syncthreads();
    if (t < 64) {
        float S1 = 0.f, S2 = 0.f;
#pragma unroll
        for (int k = 0; k < 16; ++k) { S1 += r1[k][t]; S2 += r2[k][t]; }
        const float g = gamma[0];
        const float invN = 1.f / 16384.f;       // B*SY
        const float mean = S1 * invN;
        const float var  = S2 * invN - mean * mean;
        const float inv  = rsqrtf(g * g * var + 1e-5f);
        const float scale = g * inv * bn_w[t];
        sc[t] = scale;
        sh[t] = bn_b[t] - mean * scale;
    }
}

// ---------------------------------------------------------------------------
// K5: epilogue.  out[b][c][4jj..4jj+3] = x + O[b][c][jj]*scale[c] + shift[c]
// ---------------------------------------------------------------------------
__global__ __launch_bounds__(256) void k_out(
    const float* __restrict__ x, const float* __restrict__ Obuf,
    const float* __restrict__ sc, const float* __restrict__ sh,
    float* __restrict__ out)
{
    const int gid = blockIdx.x * 256 + threadIdx.x;   // 0 .. B*CX*SY-1
    const int c = (gid >> 11) & 63;
    const float o  = Obuf[gid];
    const float4 xv = reinterpret_cast<const float4*>(x)[gid];
    const float val = o * sc[c] + sh[c];
    float4 r;
    r.x = xv.x + val; r.y = xv.y + val; r.z = xv.z + val; r.w = xv.w + val;
    reinterpret_cast<float4*>(out)[gid] = r;
}

extern "C" void kernel_launch(void* const* d_in, const int* in_sizes, int n_in,
                              void* d_out, int out_size, void* d_ws, size_t ws_size,
                              hipStream_t stream)
{
    (void)in_sizes; (void)n_in; (void)out_size; (void)ws_size;
    const float* x  = (const float*)d_in[0];
    const float* y  = (const float*)d_in[1];
    const float* wq = (const float*)d_in[2];
    const float* bq = (const float*)d_in[3];
    const float* wk = (const float*)d_in[4];
    const float* bk = (const float*)d_in[5];
    const float* wv = (const float*)d_in[6];
    const float* bv = (const float*)d_in[7];
    const float* gm = (const float*)d_in[8];
    const float* bw = (const float*)d_in[9];
    const float* bb = (const float*)d_in[10];

    char* ws = (char*)d_ws;
    ushort_t* qT  = (ushort_t*)(ws + OFF_Q);
    ushort_t* kT  = (ushort_t*)(ws + OFF_K);
    ushort_t* vBp = (ushort_t*)(ws + OFF_V);
    float*    Ob  = (float*)(ws + OFF_O);
    float*    p1  = (float*)(ws + OFF_P1);
    float*    p2  = (float*)(ws + OFF_P2);
    float*    scp = (float*)(ws + OFF_SC);
    float*    shp = (float*)(ws + OFF_SH);

    k_qk  <<<256, 1024, 0, stream>>>(y, wq, bq, wk, bk, qT, kT);
    k_v   <<<256, 1024, 0, stream>>>(x, wv, bv, vBp);
    k_attn<<<256, 1024, 0, stream>>>(qT, kT, vBp, Ob, p1, p2);
    k_bn  <<<1,   1024, 0, stream>>>(p1, p2, gm, bw, bb, scp, shp);
    k_out <<<4096, 256, 0, stream>>>(x, Ob, scp, shp, (float*)d_out);
}

// Round 10
// 131.048 us; speedup vs baseline: 1.1103x; 1.0162x over previous
//
#include <hip/hip_runtime.h>
#include <hip/hip_bf16.h>

typedef __attribute__((ext_vector_type(8))) short short8;
typedef __attribute__((ext_vector_type(4))) float f32x4;
typedef unsigned short ushort_t;
typedef unsigned int uint_t;

// Fixed problem dims
static constexpr int B  = 8;
static constexpr int CX = 64;
static constexpr int SX = 8192;   // 128*64
static constexpr int CY = 256;
static constexpr int SY = 2048;   // 64*32
static constexpr int D  = 32;     // Cy/8

// workspace layout (byte offsets)
static constexpr size_t OFF_Q  = 0;                          // bf16 [B][SY][D]   1 MB
static constexpr size_t OFF_K  = OFF_Q + (size_t)B*SY*D*2;   // bf16 [B][SY][D]   1 MB
static constexpr size_t OFF_V  = OFF_K + (size_t)B*SY*D*2;   // bf16 [B][CX][SY]  2 MB (c-major!)
static constexpr size_t OFF_O  = OFF_V + (size_t)B*CX*SY*2;  // f32  [B][CX][SY]  4 MB
static constexpr size_t OFF_P1 = OFF_O + (size_t)B*CX*SY*4;  // f32  [256][64]
static constexpr size_t OFF_P2 = OFF_P1 + 512*64*4;          // f32  [256][64]
static constexpr size_t OFF_SC = OFF_P2 + 512*64*4;          // f32  [64]
static constexpr size_t OFF_SH = OFF_SC + 64*4;              // f32  [64]

__device__ inline ushort_t f2bf(float f) {                   // RNE f32->bf16
    uint_t u = __builtin_bit_cast(uint_t, f);
    u += 0x7fffu + ((u >> 16) & 1u);
    return (ushort_t)(u >> 16);
}
__device__ inline uint_t pack_bf16(float a, float b) {       // (lo=a, hi=b)
    uint_t ua = __builtin_bit_cast(uint_t, a);
    uint_t ub = __builtin_bit_cast(uint_t, b);
    ua += 0x7fffu + ((ua >> 16) & 1u);
    ub += 0x7fffu + ((ub >> 16) & 1u);
    return (ua >> 16) | (ub & 0xffff0000u);
}

// ---------------------------------------------------------------------------
// K1 v2: q/k 1x1 conv via MFMA -> bf16 qT/kT [b][s][32]. (unchanged from R9)
// ---------------------------------------------------------------------------
__global__ __launch_bounds__(1024) void k_qk(
    const float* __restrict__ y, const float* __restrict__ wq,
    const float* __restrict__ bq, const float* __restrict__ wk,
    const float* __restrict__ bk, ushort_t* __restrict__ qT, ushort_t* __restrict__ kT)
{
    __shared__ __align__(16) unsigned char Wl[32768];   // [64 o][256 c] bf16, rows 512B, swz
    __shared__ __align__(16) unsigned char Yl[32768];   // [64 s][256 c] bf16, rows 512B, swz
    const int t  = threadIdx.x;
    const int b  = blockIdx.x >> 5;
    const int s0 = (blockIdx.x & 31) << 6;

#pragma unroll
    for (int p = 0; p < 8; ++p) {
        const int idx = p * 1024 + t;           // 0..8191
        const int o   = idx >> 7;               // 0..63
        const int c2  = idx & 127;              // c-pair index
        const float f0 = (o < 32) ? wq[o * CY + 2 * c2]     : wk[(o - 32) * CY + 2 * c2];
        const float f1 = (o < 32) ? wq[o * CY + 2 * c2 + 1] : wk[(o - 32) * CY + 2 * c2 + 1];
        *reinterpret_cast<uint_t*>(Wl + ((o * 512 + c2 * 4) ^ ((o & 7) << 4))) = pack_bf16(f0, f1);
    }
    {
        const int l = t & 63, cg = t >> 6;
        const float* ysrc = y + (size_t)(b * CY + cg * 16) * SY + s0 + l;
#pragma unroll
        for (int k = 0; k < 8; ++k) {
            const float f0 = ysrc[(2 * k)     * SY];
            const float f1 = ysrc[(2 * k + 1) * SY];
            const int c = cg * 16 + 2 * k;
            *reinterpret_cast<uint_t*>(Yl + ((l * 512 + c * 2) ^ ((l & 7) << 4))) = pack_bf16(f0, f1);
        }
    }
    __syncthreads();

    const int w  = t >> 6, l = t & 63;
    const int li = l & 15, g = l >> 4;
    const int ot = w & 3,  st = w >> 2;
    const int oo = ot * 16 + li;                // A row (o)
    const int ss = st * 16 + li;                // B col (s)

    f32x4 acc = (f32x4){0.f, 0.f, 0.f, 0.f};
#pragma unroll
    for (int ch = 0; ch < 8; ++ch) {
        const short8 wf = *reinterpret_cast<const short8*>(
            Wl + ((oo * 512 + ch * 64 + g * 16) ^ ((oo & 7) << 4)));
        const short8 yf = *reinterpret_cast<const short8*>(
            Yl + ((ss * 512 + ch * 64 + g * 16) ^ ((ss & 7) << 4)));
        acc = __builtin_amdgcn_mfma_f32_16x16x32_bf16(wf, yf, acc, 0, 0, 0);
    }
    const float* bias = (ot < 2) ? bq : bk;
    const int ob = (ot & 1) * 16 + g * 4;
    const float v0 = acc[0] + bias[ob + 0];
    const float v1 = acc[1] + bias[ob + 1];
    const float v2 = acc[2] + bias[ob + 2];
    const float v3 = acc[3] + bias[ob + 3];
    uint2 pw; pw.x = pack_bf16(v0, v1); pw.y = pack_bf16(v2, v3);
    ushort_t* dst = (ot < 2) ? qT : kT;
    *reinterpret_cast<uint2*>(dst + (size_t)(b * SY + s0 + ss) * D + ob) = pw;
}

// ---------------------------------------------------------------------------
// K2: pooled v -> bf16 vB [b][c][j] (c-major). (unchanged)
// ---------------------------------------------------------------------------
__global__ __launch_bounds__(1024) void k_v(
    const float* __restrict__ x, const float* __restrict__ wv,
    const float* __restrict__ bv, ushort_t* __restrict__ vB)
{
    __shared__ __align__(16) float xp[64][68];
    __shared__ __align__(16) float wt[64][68];
    const int t   = threadIdx.x;
    const int b   = blockIdx.x >> 5;
    const int jj0 = (blockIdx.x & 31) << 6;

#pragma unroll
    for (int p = 0; p < 4; ++p) {
        const int f = p * 1024 + t;
        const int co = f >> 6, ci = f & 63;
        wt[ci][co] = wv[co * 64 + ci];
    }
    {
        const float4* x4 = reinterpret_cast<const float4*>(x);
#pragma unroll
        for (int p = 0; p < 4; ++p) {
            const int f = p * 1024 + t;
            const int ci = f >> 6, j = f & 63;
            const float4 v = x4[(size_t)(b * CX + ci) * (SX / 4) + jj0 + j];
            xp[ci][j] = (v.x + v.y) + (v.z + v.w);
        }
    }
    __syncthreads();

    const int w = t >> 6, j = t & 63;
    float a0 = 0.f, a1 = 0.f, a2 = 0.f, a3 = 0.f;
#pragma unroll 4
    for (int ci = 0; ci < 64; ++ci) {
        const float xv = xp[ci][j];
        const float4 w4 = *reinterpret_cast<const float4*>(&wt[ci][w * 4]);
        a0 += w4.x * xv; a1 += w4.y * xv; a2 += w4.z * xv; a3 += w4.w * xv;
    }
    const int c0 = w * 4;
    const size_t base = (size_t)(b * CX) * SY + jj0 + j;
    vB[base + (size_t)(c0 + 0) * SY] = f2bf(a0 + 4.f * bv[c0 + 0]);
    vB[base + (size_t)(c0 + 1) * SY] = f2bf(a1 + 4.f * bv[c0 + 1]);
    vB[base + (size_t)(c0 + 2) * SY] = f2bf(a2 + 4.f * bv[c0 + 2]);
    vB[base + (size_t)(c0 + 3) * SY] = f2bf(a3 + 4.f * bv[c0 + 3]);
}

// ---------------------------------------------------------------------------
// K3 v5: single-barrier-per-chunk MFMA flash attention.
// grid 256 (b x 32 slabs of 64 i-rows), block 1024 = 16 waves.
// Wave w owns (i-tile m = w&3, j-quarter jq = w>>2): runs QK -> exp ->
// P write (WAVE-PRIVATE LDS tile, 16 rows x 80B stride: no publish barrier)
// -> PV as one uninterrupted stream. K (8KB) + V (16KB, source-pre-swizzled)
// reg-staged double-buffered; ONE __syncthreads per chunk (staging publish;
// it drains lgkm/vm so dbuf rotation is race-free).
// Epilogue: 4-round jq-merge into Otile, invL, BN partials, coalesced O write.
// ---------------------------------------------------------------------------
__global__ __launch_bounds__(1024) void k_attn(
    const ushort_t* __restrict__ qT, const ushort_t* __restrict__ kT,
    const ushort_t* __restrict__ vB, float* __restrict__ O,
    float* __restrict__ part1, float* __restrict__ part2)
{
    __shared__ __align__(16) unsigned char smem[69632];
    unsigned char* Kb0 = smem;            // [128 j][32 d] bf16 linear, 8KB
    unsigned char* Kb1 = smem + 8192;
    unsigned char* Vb0 = smem + 16384;    // [64 c][128 j] bf16, XOR-swz, 16KB
    unsigned char* Vb1 = smem + 32768;
    unsigned char* Pw  = smem + 49152;    // 16 waves x [16 i][80B] = 20KB
    // epilogue overlay (post-loop, barrier-separated)
    float* Otile = reinterpret_cast<float*>(smem);           // [64 c][68 pad] f32
    float* Lpart = reinterpret_cast<float*>(smem + 17408);   // [4 jq][64 i]
    float* invL  = reinterpret_cast<float*>(smem + 18432);   // [64 i]

    const int t  = threadIdx.x;
    const int w  = t >> 6, l = t & 63;
    const int g  = l >> 4, li = l & 15;
    const int b  = blockIdx.x >> 5;
    const int i0 = (blockIdx.x & 31) << 6;

    const int m  = w & 3;                  // i-tile
    const int jq = w >> 2;                 // j-quarter within 128-j chunk

    const ushort_t* kb = kT + (size_t)b * SY * D;
    const ushort_t* vb = vB + (size_t)b * CX * SY;

    // Q B-fragment for this wave's i-tile
    const short8 qf = *reinterpret_cast<const short8*>(
        qT + ((size_t)(b * SY + i0 + m * 16 + li)) * D + g * 8);

    // staging addresses (same as validated R6 pattern)
    const int koff = w * 1024 + l * 16;                 // waves 0..7: K flat slice
    const int vc = w * 4 + g;                           // V: c-row
    const int vldso = vc * 256 + li * 16;               // V LDS offset (linear)
    const unsigned char* kgb = reinterpret_cast<const unsigned char*>(kb);
    const unsigned char* vgb = reinterpret_cast<const unsigned char*>(vb)
                             + (size_t)vc * (SY * 2) + ((li ^ (vc & 7)) * 16);

    unsigned char* Pme = Pw + w * 1280;                 // private tile, rows 80B
    const int swzV = (li & 7) << 4;

    f32x4 acc[4];
#pragma unroll
    for (int n = 0; n < 4; ++n) acc[n] = (f32x4){0.f, 0.f, 0.f, 0.f};
    float lsum = 0.f;

    // prologue: stage chunk 0 into buf0
    {
        short8 kr, vr;
        if (w < 8) kr = *reinterpret_cast<const short8*>(kgb + koff);
        vr = *reinterpret_cast<const short8*>(vgb);
        if (w < 8) *reinterpret_cast<short8*>(Kb0 + koff) = kr;
        *reinterpret_cast<short8*>(Vb0 + vldso) = vr;
    }
    __syncthreads();

    for (int ch = 0; ch < 16; ++ch) {
        unsigned char* Kc = (ch & 1) ? Kb1 : Kb0;
        unsigned char* Vc = (ch & 1) ? Vb1 : Vb0;
        unsigned char* Kn = (ch & 1) ? Kb0 : Kb1;
        unsigned char* Vn = (ch & 1) ? Vb0 : Vb1;

        // issue next-chunk global loads early (latency hides under compute)
        short8 kr, vr;
        if (ch < 15) {
            if (w < 8) kr = *reinterpret_cast<const short8*>(kgb + (size_t)(ch + 1) * 8192 + koff);
            vr = *reinterpret_cast<const short8*>(vgb + (size_t)(ch + 1) * 256);
        }

        // --- QK (swapped): two 16-j tiles of this wave's 32-j quarter ---
        const short8 kf0 = *reinterpret_cast<const short8*>(Kc + (jq * 32 + li) * 64 + g * 16);
        const short8 kf1 = *reinterpret_cast<const short8*>(Kc + (jq * 32 + 16 + li) * 64 + g * 16);
        const f32x4 d0 = __builtin_amdgcn_mfma_f32_16x16x32_bf16(kf0, qf, (f32x4){0.f,0.f,0.f,0.f}, 0, 0, 0);
        const f32x4 d1 = __builtin_amdgcn_mfma_f32_16x16x32_bf16(kf1, qf, (f32x4){0.f,0.f,0.f,0.f}, 0, 0, 0);

        // --- exp + pack + private P write (lane: i=li, j=4g+r / 16+4g+r) ---
        {
            const float e0 = __expf(d0[0]), e1 = __expf(d0[1]);
            const float e2 = __expf(d0[2]), e3 = __expf(d0[3]);
            const float h0 = __expf(d1[0]), h1 = __expf(d1[1]);
            const float h2 = __expf(d1[2]), h3 = __expf(d1[3]);
            lsum += ((e0 + e1) + (e2 + e3)) + ((h0 + h1) + (h2 + h3));
            uint2 p0; p0.x = pack_bf16(e0, e1); p0.y = pack_bf16(e2, e3);
            *reinterpret_cast<uint2*>(Pme + li * 80 + 8 * g) = p0;
            uint2 p1; p1.x = pack_bf16(h0, h1); p1.y = pack_bf16(h2, h3);
            *reinterpret_cast<uint2*>(Pme + li * 80 + 32 + 8 * g) = p1;
        }

        // --- PV: one private pf read reused for 4 mfmas ---
        const short8 pf = *reinterpret_cast<const short8*>(Pme + li * 80 + 16 * g);
#pragma unroll
        for (int n = 0; n < 4; ++n) {
            const short8 vf = *reinterpret_cast<const short8*>(
                Vc + (n * 16 + li) * 256 + ((jq * 64 + g * 16) ^ swzV));
            acc[n] = __builtin_amdgcn_mfma_f32_16x16x32_bf16(pf, vf, acc[n], 0, 0, 0);
        }

        // write staged regs into next buffers, single barrier
        if (ch < 15) {
            if (w < 8) *reinterpret_cast<short8*>(Kn + koff) = kr;
            *reinterpret_cast<short8*>(Vn + vldso) = vr;
        }
        __syncthreads();
    }

    // ---- epilogue (all K/V/P reads done; overlay smem) ----
    lsum += __shfl_xor(lsum, 16, 64);
    lsum += __shfl_xor(lsum, 32, 64);
    if (l < 16) Lpart[jq * 64 + m * 16 + l] = lsum;

    if (jq == 0) {
#pragma unroll
        for (int n = 0; n < 4; ++n) {
            *reinterpret_cast<float4*>(&Otile[(n * 16 + li) * 68 + m * 16 + g * 4]) =
                make_float4(acc[n][0], acc[n][1], acc[n][2], acc[n][3]);
        }
    }
    __syncthreads();
    if (t < 64) {
        float L = 0.f;
#pragma unroll
        for (int jj = 0; jj < 4; ++jj) L += Lpart[jj * 64 + t];
        invL[t] = 1.f / L;
    }
    if (jq == 1) {
#pragma unroll
        for (int n = 0; n < 4; ++n) {
            float4* p = reinterpret_cast<float4*>(&Otile[(n * 16 + li) * 68 + m * 16 + g * 4]);
            float4 v = *p;
            v.x += acc[n][0]; v.y += acc[n][1]; v.z += acc[n][2]; v.w += acc[n][3];
            *p = v;
        }
    }
    __syncthreads();
    if (jq == 2) {
#pragma unroll
        for (int n = 0; n < 4; ++n) {
            float4* p = reinterpret_cast<float4*>(&Otile[(n * 16 + li) * 68 + m * 16 + g * 4]);
            float4 v = *p;
            v.x += acc[n][0]; v.y += acc[n][1]; v.z += acc[n][2]; v.w += acc[n][3];
            *p = v;
        }
    }
    __syncthreads();
    if (jq == 3) {
#pragma unroll
        for (int n = 0; n < 4; ++n) {
            float4* p = reinterpret_cast<float4*>(&Otile[(n * 16 + li) * 68 + m * 16 + g * 4]);
            float4 v = *p;
            v.x += acc[n][0]; v.y += acc[n][1]; v.z += acc[n][2]; v.w += acc[n][3];
            *p = v;
        }
    }
    __syncthreads();

    // BN partial sums over this block's 64 i-rows (normalized O, pre-gamma)
    if (t < 64) {
        float sa = 0.f, sq = 0.f;
        for (int i = 0; i < 64; ++i) {
            const float v = Otile[t * 68 + i] * invL[i];
            sa += v; sq += v * v;
        }
        part1[blockIdx.x * 64 + t] = sa;
        part2[blockIdx.x * 64 + t] = sq;
    }

    // coalesced transposed write: O[b][c][i0..i0+63]
    {
        const int c = t >> 4, i4 = t & 15;
        float4 o;
        o.x = Otile[c * 68 + i4 * 4 + 0] * invL[i4 * 4 + 0];
        o.y = Otile[c * 68 + i4 * 4 + 1] * invL[i4 * 4 + 1];
        o.z = Otile[c * 68 + i4 * 4 + 2] * invL[i4 * 4 + 2];
        o.w = Otile[c * 68 + i4 * 4 + 3] * invL[i4 * 4 + 3];
        reinterpret_cast<float4*>(O)[(size_t)(b * CX + c) * (SY / 4) + (i0 >> 2) + i4] = o;
    }
}

// ---------------------------------------------------------------------------
// K4: reduce 256-block BN partials -> per-channel scale/shift. block 1024.
// ---------------------------------------------------------------------------
__global__ __launch_bounds__(1024) void k_bn(
    const float* __restrict__ part1, const float* __restrict__ part2,
    const float* __restrict__ gamma, const float* __restrict__ bn_w,
    const float* __restrict__ bn_b, float* __restrict__ sc,
    float* __restrict__ sh)
{
    __shared__ float r1[16][64], r2[16][64];
    const int t = threadIdx.x;
    const int c = t & 63, q = t >> 6;
    float s1 = 0.f, s2 = 0.f;
#pragma unroll
    for (int n = 0; n < 16; ++n) {
        const int row = n * 16 + q;
        s1 += part1[row * 64 + c];
        s2 += part2[row * 64 + c];
    }
    r1[q][c] = s1; r2[q][c] = s2;
    __syncthreads();
    if (t < 64) {
        float S1 = 0.f, S2 = 0.f;
#pragma unroll
        for (int k = 0; k < 16; ++k) { S1 += r1[k][t]; S2 += r2[k][t]; }
        const float g = gamma[0];
        const float invN = 1.f / 16384.f;       // B*SY
        const float mean = S1 * invN;
        const float var  = S2 * invN - mean * mean;
        const float inv  = rsqrtf(g * g * var + 1e-5f);
        const float scale = g * inv * bn_w[t];
        sc[t] = scale;
        sh[t] = bn_b[t] - mean * scale;
    }
}

// ---------------------------------------------------------------------------
// K5: epilogue.  out[b][c][4jj..4jj+3] = x + O[b][c][jj]*scale[c] + shift[c]
// ---------------------------------------------------------------------------
__global__ __launch_bounds__(256) void k_out(
    const float* __restrict__ x, const float* __restrict__ Obuf,
    const float* __restrict__ sc, const float* __restrict__ sh,
    float* __restrict__ out)
{
    const int gid = blockIdx.x * 256 + threadIdx.x;   // 0 .. B*CX*SY-1
    const int c = (gid >> 11) & 63;
    const float o  = Obuf[gid];
    const float4 xv = reinterpret_cast<const float4*>(x)[gid];
    const float val = o * sc[c] + sh[c];
    float4 r;
    r.x = xv.x + val; r.y = xv.y + val; r.z = xv.z + val; r.w = xv.w + val;
    reinterpret_cast<float4*>(out)[gid] = r;
}

extern "C" void kernel_launch(void* const* d_in, const int* in_sizes, int n_in,
                              void* d_out, int out_size, void* d_ws, size_t ws_size,
                              hipStream_t stream)
{
    (void)in_sizes; (void)n_in; (void)out_size; (void)ws_size;
    const float* x  = (const float*)d_in[0];
    const float* y  = (const float*)d_in[1];
    const float* wq = (const float*)d_in[2];
    const float* bq = (const float*)d_in[3];
    const float* wk = (const float*)d_in[4];
    const float* bk = (const float*)d_in[5];
    const float* wv = (const float*)d_in[6];
    const float* bv = (const float*)d_in[7];
    const float* gm = (const float*)d_in[8];
    const float* bw = (const float*)d_in[9];
    const float* bb = (const float*)d_in[10];

    char* ws = (char*)d_ws;
    ushort_t* qT  = (ushort_t*)(ws + OFF_Q);
    ushort_t* kT  = (ushort_t*)(ws + OFF_K);
    ushort_t* vBp = (ushort_t*)(ws + OFF_V);
    float*    Ob  = (float*)(ws + OFF_O);
    float*    p1  = (float*)(ws + OFF_P1);
    float*    p2  = (float*)(ws + OFF_P2);
    float*    scp = (float*)(ws + OFF_SC);
    float*    shp = (float*)(ws + OFF_SH);

    k_qk  <<<256, 1024, 0, stream>>>(y, wq, bq, wk, bk, qT, kT);
    k_v   <<<256, 1024, 0, stream>>>(x, wv, bv, vBp);
    k_attn<<<256, 1024, 0, stream>>>(qT, kT, vBp, Ob, p1, p2);
    k_bn  <<<1,   1024, 0, stream>>>(p1, p2, gm, bw, bb, scp, shp);
    k_out <<<4096, 256, 0, stream>>>(x, Ob, scp, shp, (float*)d_out);
}

// Round 11
// 126.177 us; speedup vs baseline: 1.1531x; 1.0386x over previous
//
#include <hip/hip_runtime.h>
#include <hip/hip_bf16.h>

typedef __attribute__((ext_vector_type(8))) short short8;
typedef __attribute__((ext_vector_type(4))) float f32x4;
typedef unsigned short ushort_t;
typedef unsigned int uint_t;

// Fixed problem dims
static constexpr int B  = 8;
static constexpr int CX = 64;
static constexpr int SX = 8192;   // 128*64
static constexpr int CY = 256;
static constexpr int SY = 2048;   // 64*32
static constexpr int D  = 32;     // Cy/8

// workspace layout (byte offsets)
static constexpr size_t OFF_Q  = 0;                          // bf16 [B][SY][D]   1 MB
static constexpr size_t OFF_K  = OFF_Q + (size_t)B*SY*D*2;   // bf16 [B][SY][D]   1 MB
static constexpr size_t OFF_V  = OFF_K + (size_t)B*SY*D*2;   // bf16 [B][CX][SY]  2 MB (c-major!)
static constexpr size_t OFF_O  = OFF_V + (size_t)B*CX*SY*2;  // f32  [B][CX][SY]  4 MB
static constexpr size_t OFF_P1 = OFF_O + (size_t)B*CX*SY*4;  // f32  [256][64]
static constexpr size_t OFF_P2 = OFF_P1 + 512*64*4;          // f32  [256][64]
static constexpr size_t OFF_SC = OFF_P2 + 512*64*4;          // f32  [64]
static constexpr size_t OFF_SH = OFF_SC + 64*4;              // f32  [64]

__device__ inline ushort_t f2bf(float f) {                   // RNE f32->bf16
    uint_t u = __builtin_bit_cast(uint_t, f);
    u += 0x7fffu + ((u >> 16) & 1u);
    return (ushort_t)(u >> 16);
}
__device__ inline uint_t pack_bf16(float a, float b) {       // (lo=a, hi=b)
    uint_t ua = __builtin_bit_cast(uint_t, a);
    uint_t ub = __builtin_bit_cast(uint_t, b);
    ua += 0x7fffu + ((ua >> 16) & 1u);
    ub += 0x7fffu + ((ub >> 16) & 1u);
    return (ua >> 16) | (ub & 0xffff0000u);
}

// ---------------------------------------------------------------------------
// K1+K2 merged: blocks 0..255 do q/k MFMA conv; blocks 256..511 do pooled v.
// Both halves are latency-bound; merging lets them overlap on the GPU.
// ---------------------------------------------------------------------------
__global__ __launch_bounds__(1024) void k_prod(
    const float* __restrict__ y, const float* __restrict__ wq,
    const float* __restrict__ bq, const float* __restrict__ wk,
    const float* __restrict__ bk, ushort_t* __restrict__ qT, ushort_t* __restrict__ kT,
    const float* __restrict__ x, const float* __restrict__ wv,
    const float* __restrict__ bv, ushort_t* __restrict__ vB)
{
    __shared__ __align__(16) unsigned char lds[65536];
    const int t = threadIdx.x;

    if (blockIdx.x < 256) {
        // ---------------- q/k via MFMA (validated R9 body) ----------------
        unsigned char* Wl = lds;            // [64 o][256 c] bf16, rows 512B, swz
        unsigned char* Yl = lds + 32768;    // [64 s][256 c] bf16, rows 512B, swz
        const int b  = blockIdx.x >> 5;
        const int s0 = (blockIdx.x & 31) << 6;

#pragma unroll
        for (int p = 0; p < 8; ++p) {
            const int idx = p * 1024 + t;           // 0..8191
            const int o   = idx >> 7;               // 0..63
            const int c2  = idx & 127;              // c-pair index
            const float f0 = (o < 32) ? wq[o * CY + 2 * c2]     : wk[(o - 32) * CY + 2 * c2];
            const float f1 = (o < 32) ? wq[o * CY + 2 * c2 + 1] : wk[(o - 32) * CY + 2 * c2 + 1];
            *reinterpret_cast<uint_t*>(Wl + ((o * 512 + c2 * 4) ^ ((o & 7) << 4))) = pack_bf16(f0, f1);
        }
        {
            const int l = t & 63, cg = t >> 6;
            const float* ysrc = y + (size_t)(b * CY + cg * 16) * SY + s0 + l;
#pragma unroll
            for (int k = 0; k < 8; ++k) {
                const float f0 = ysrc[(2 * k)     * SY];
                const float f1 = ysrc[(2 * k + 1) * SY];
                const int c = cg * 16 + 2 * k;
                *reinterpret_cast<uint_t*>(Yl + ((l * 512 + c * 2) ^ ((l & 7) << 4))) = pack_bf16(f0, f1);
            }
        }
        __syncthreads();

        const int w  = t >> 6, l = t & 63;
        const int li = l & 15, g = l >> 4;
        const int ot = w & 3,  st = w >> 2;
        const int oo = ot * 16 + li;                // A row (o)
        const int ss = st * 16 + li;                // B col (s)

        f32x4 acc = (f32x4){0.f, 0.f, 0.f, 0.f};
#pragma unroll
        for (int ch = 0; ch < 8; ++ch) {
            const short8 wf = *reinterpret_cast<const short8*>(
                Wl + ((oo * 512 + ch * 64 + g * 16) ^ ((oo & 7) << 4)));
            const short8 yf = *reinterpret_cast<const short8*>(
                Yl + ((ss * 512 + ch * 64 + g * 16) ^ ((ss & 7) << 4)));
            acc = __builtin_amdgcn_mfma_f32_16x16x32_bf16(wf, yf, acc, 0, 0, 0);
        }
        const float* bias = (ot < 2) ? bq : bk;
        const int ob = (ot & 1) * 16 + g * 4;
        const float v0 = acc[0] + bias[ob + 0];
        const float v1 = acc[1] + bias[ob + 1];
        const float v2 = acc[2] + bias[ob + 2];
        const float v3 = acc[3] + bias[ob + 3];
        uint2 pw; pw.x = pack_bf16(v0, v1); pw.y = pack_bf16(v2, v3);
        ushort_t* dst = (ot < 2) ? qT : kT;
        *reinterpret_cast<uint2*>(dst + (size_t)(b * SY + s0 + ss) * D + ob) = pw;
    } else {
        // ---------------- pooled v (validated body, LDS via pointers) ------
        float* xp = reinterpret_cast<float*>(lds);            // [64][68]
        float* wt = reinterpret_cast<float*>(lds + 17408);    // [64][68]
        const int bid = blockIdx.x - 256;
        const int b   = bid >> 5;
        const int jj0 = (bid & 31) << 6;

#pragma unroll
        for (int p = 0; p < 4; ++p) {
            const int f = p * 1024 + t;
            const int co = f >> 6, ci = f & 63;
            wt[ci * 68 + co] = wv[co * 64 + ci];
        }
        {
            const float4* x4 = reinterpret_cast<const float4*>(x);
#pragma unroll
            for (int p = 0; p < 4; ++p) {
                const int f = p * 1024 + t;
                const int ci = f >> 6, j = f & 63;
                const float4 v = x4[(size_t)(b * CX + ci) * (SX / 4) + jj0 + j];
                xp[ci * 68 + j] = (v.x + v.y) + (v.z + v.w);
            }
        }
        __syncthreads();

        const int w = t >> 6, j = t & 63;
        float a0 = 0.f, a1 = 0.f, a2 = 0.f, a3 = 0.f;
#pragma unroll 4
        for (int ci = 0; ci < 64; ++ci) {
            const float xv = xp[ci * 68 + j];
            const float4 w4 = *reinterpret_cast<const float4*>(&wt[ci * 68 + w * 4]);
            a0 += w4.x * xv; a1 += w4.y * xv; a2 += w4.z * xv; a3 += w4.w * xv;
        }
        const int c0 = w * 4;
        const size_t base = (size_t)(b * CX) * SY + jj0 + j;
        vB[base + (size_t)(c0 + 0) * SY] = f2bf(a0 + 4.f * bv[c0 + 0]);
        vB[base + (size_t)(c0 + 1) * SY] = f2bf(a1 + 4.f * bv[c0 + 1]);
        vB[base + (size_t)(c0 + 2) * SY] = f2bf(a2 + 4.f * bv[c0 + 2]);
        vB[base + (size_t)(c0 + 3) * SY] = f2bf(a3 + 4.f * bv[c0 + 3]);
    }
}

// ---------------------------------------------------------------------------
// K3 v6: K-direct-from-global flash attention (single barrier per chunk).
// grid 256 (b x 32 slabs of 64 i-rows), block 1024 = 16 waves.
// Wave w owns (i-tile m = w&3, j-quarter jq = w>>2). K fragments are read
// straight from global (coalesced 1KB tiles, L2-hot) with a 1-chunk register
// prefetch — K never touches LDS. V (16KB, source-pre-swizzled) stays
// reg-staged double-buffered in LDS; P is a wave-private 16x80B tile.
// LDS 52KB. One __syncthreads per chunk (V dbuf publish).
// ---------------------------------------------------------------------------
__global__ __launch_bounds__(1024) void k_attn(
    const ushort_t* __restrict__ qT, const ushort_t* __restrict__ kT,
    const ushort_t* __restrict__ vB, float* __restrict__ O,
    float* __restrict__ part1, float* __restrict__ part2)
{
    __shared__ __align__(16) unsigned char smem[53248];
    unsigned char* Vb0 = smem;            // [64 c][128 j] bf16, XOR-swz, 16KB
    unsigned char* Vb1 = smem + 16384;
    unsigned char* Pw  = smem + 32768;    // 16 waves x [16 i][80B] = 20KB
    // epilogue overlay (post-loop, barrier-separated)
    float* Otile = reinterpret_cast<float*>(smem);           // [64 c][68 pad] f32
    float* Lpart = reinterpret_cast<float*>(smem + 17408);   // [4 jq][64 i]
    float* invL  = reinterpret_cast<float*>(smem + 18432);   // [64 i]

    const int t  = threadIdx.x;
    const int w  = t >> 6, l = t & 63;
    const int g  = l >> 4, li = l & 15;
    const int b  = blockIdx.x >> 5;
    const int i0 = (blockIdx.x & 31) << 6;

    const int m  = w & 3;                  // i-tile
    const int jq = w >> 2;                 // j-quarter within 128-j chunk

    const ushort_t* kb = kT + (size_t)b * SY * D;
    const ushort_t* vb = vB + (size_t)b * CX * SY;

    // Q B-fragment for this wave's i-tile
    const short8 qf = *reinterpret_cast<const short8*>(
        qT + ((size_t)(b * SY + i0 + m * 16 + li)) * D + g * 8);

    // K global addresses: tile of 16 rows x 64B is 1KB contiguous, coalesced.
    const unsigned char* kgb = reinterpret_cast<const unsigned char*>(kb)
                             + (jq * 32 + li) * 64 + g * 16;
    // V staging addresses (validated pattern)
    const int vc = w * 4 + g;                           // V: c-row
    const int vldso = vc * 256 + li * 16;               // V LDS offset (linear)
    const unsigned char* vgb = reinterpret_cast<const unsigned char*>(vb)
                             + (size_t)vc * (SY * 2) + ((li ^ (vc & 7)) * 16);

    unsigned char* Pme = Pw + w * 1280;                 // private tile, rows 80B
    const int swzV = (li & 7) << 4;

    f32x4 acc[4];
#pragma unroll
    for (int n = 0; n < 4; ++n) acc[n] = (f32x4){0.f, 0.f, 0.f, 0.f};
    float lsum = 0.f;

    // prologue: stage V chunk 0; load K chunk 0 into regs
    short8 kc0 = *reinterpret_cast<const short8*>(kgb);
    short8 kc1 = *reinterpret_cast<const short8*>(kgb + 16 * 64);
    {
        const short8 vr = *reinterpret_cast<const short8*>(vgb);
        *reinterpret_cast<short8*>(Vb0 + vldso) = vr;
    }
    __syncthreads();

    for (int ch = 0; ch < 16; ++ch) {
        unsigned char* Vc = (ch & 1) ? Vb1 : Vb0;
        unsigned char* Vn = (ch & 1) ? Vb0 : Vb1;

        // prefetch next chunk: K into regs, V into reg for late LDS write
        short8 kn0, kn1, vr;
        if (ch < 15) {
            kn0 = *reinterpret_cast<const short8*>(kgb + (size_t)(ch + 1) * 8192);
            kn1 = *reinterpret_cast<const short8*>(kgb + (size_t)(ch + 1) * 8192 + 1024);
            vr  = *reinterpret_cast<const short8*>(vgb + (size_t)(ch + 1) * 256);
        }

        // --- QK (swapped): two 16-j tiles of this wave's 32-j quarter ---
        const f32x4 d0 = __builtin_amdgcn_mfma_f32_16x16x32_bf16(kc0, qf, (f32x4){0.f,0.f,0.f,0.f}, 0, 0, 0);
        const f32x4 d1 = __builtin_amdgcn_mfma_f32_16x16x32_bf16(kc1, qf, (f32x4){0.f,0.f,0.f,0.f}, 0, 0, 0);

        // --- exp + pack + private P write (lane: i=li, j=4g+r / 16+4g+r) ---
        {
            const float e0 = __expf(d0[0]), e1 = __expf(d0[1]);
            const float e2 = __expf(d0[2]), e3 = __expf(d0[3]);
            const float h0 = __expf(d1[0]), h1 = __expf(d1[1]);
            const float h2 = __expf(d1[2]), h3 = __expf(d1[3]);
            lsum += ((e0 + e1) + (e2 + e3)) + ((h0 + h1) + (h2 + h3));
            uint2 p0; p0.x = pack_bf16(e0, e1); p0.y = pack_bf16(e2, e3);
            *reinterpret_cast<uint2*>(Pme + li * 80 + 8 * g) = p0;
            uint2 p1; p1.x = pack_bf16(h0, h1); p1.y = pack_bf16(h2, h3);
            *reinterpret_cast<uint2*>(Pme + li * 80 + 32 + 8 * g) = p1;
        }

        // --- PV: one private pf read reused for 4 mfmas ---
        const short8 pf = *reinterpret_cast<const short8*>(Pme + li * 80 + 16 * g);
#pragma unroll
        for (int n = 0; n < 4; ++n) {
            const short8 vf = *reinterpret_cast<const short8*>(
                Vc + (n * 16 + li) * 256 + ((jq * 64 + g * 16) ^ swzV));
            acc[n] = __builtin_amdgcn_mfma_f32_16x16x32_bf16(pf, vf, acc[n], 0, 0, 0);
        }

        // late V write into next buffer, single barrier
        if (ch < 15) {
            *reinterpret_cast<short8*>(Vn + vldso) = vr;
        }
        __syncthreads();
        kc0 = kn0; kc1 = kn1;
    }

    // ---- epilogue (all V/P reads done; overlay smem) ----
    lsum += __shfl_xor(lsum, 16, 64);
    lsum += __shfl_xor(lsum, 32, 64);
    if (l < 16) Lpart[jq * 64 + m * 16 + l] = lsum;

    if (jq == 0) {
#pragma unroll
        for (int n = 0; n < 4; ++n) {
            *reinterpret_cast<float4*>(&Otile[(n * 16 + li) * 68 + m * 16 + g * 4]) =
                make_float4(acc[n][0], acc[n][1], acc[n][2], acc[n][3]);
        }
    }
    __syncthreads();
    if (t < 64) {
        float L = 0.f;
#pragma unroll
        for (int jj = 0; jj < 4; ++jj) L += Lpart[jj * 64 + t];
        invL[t] = 1.f / L;
    }
    if (jq == 1) {
#pragma unroll
        for (int n = 0; n < 4; ++n) {
            float4* p = reinterpret_cast<float4*>(&Otile[(n * 16 + li) * 68 + m * 16 + g * 4]);
            float4 v = *p;
            v.x += acc[n][0]; v.y += acc[n][1]; v.z += acc[n][2]; v.w += acc[n][3];
            *p = v;
        }
    }
    __syncthreads();
    if (jq == 2) {
#pragma unroll
        for (int n = 0; n < 4; ++n) {
            float4* p = reinterpret_cast<float4*>(&Otile[(n * 16 + li) * 68 + m * 16 + g * 4]);
            float4 v = *p;
            v.x += acc[n][0]; v.y += acc[n][1]; v.z += acc[n][2]; v.w += acc[n][3];
            *p = v;
        }
    }
    __syncthreads();
    if (jq == 3) {
#pragma unroll
        for (int n = 0; n < 4; ++n) {
            float4* p = reinterpret_cast<float4*>(&Otile[(n * 16 + li) * 68 + m * 16 + g * 4]);
            float4 v = *p;
            v.x += acc[n][0]; v.y += acc[n][1]; v.z += acc[n][2]; v.w += acc[n][3];
            *p = v;
        }
    }
    __syncthreads();

    // BN partial sums over this block's 64 i-rows (normalized O, pre-gamma)
    if (t < 64) {
        float sa = 0.f, sq = 0.f;
        for (int i = 0; i < 64; ++i) {
            const float v = Otile[t * 68 + i] * invL[i];
            sa += v; sq += v * v;
        }
        part1[blockIdx.x * 64 + t] = sa;
        part2[blockIdx.x * 64 + t] = sq;
    }

    // coalesced transposed write: O[b][c][i0..i0+63]
    {
        const int c = t >> 4, i4 = t & 15;
        float4 o;
        o.x = Otile[c * 68 + i4 * 4 + 0] * invL[i4 * 4 + 0];
        o.y = Otile[c * 68 + i4 * 4 + 1] * invL[i4 * 4 + 1];
        o.z = Otile[c * 68 + i4 * 4 + 2] * invL[i4 * 4 + 2];
        o.w = Otile[c * 68 + i4 * 4 + 3] * invL[i4 * 4 + 3];
        reinterpret_cast<float4*>(O)[(size_t)(b * CX + c) * (SY / 4) + (i0 >> 2) + i4] = o;
    }
}

// ---------------------------------------------------------------------------
// K4: reduce 256-block BN partials -> per-channel scale/shift. block 1024.
// ---------------------------------------------------------------------------
__global__ __launch_bounds__(1024) void k_bn(
    const float* __restrict__ part1, const float* __restrict__ part2,
    const float* __restrict__ gamma, const float* __restrict__ bn_w,
    const float* __restrict__ bn_b, float* __restrict__ sc,
    float* __restrict__ sh)
{
    __shared__ float r1[16][64], r2[16][64];
    const int t = threadIdx.x;
    const int c = t & 63, q = t >> 6;
    float s1 = 0.f, s2 = 0.f;
#pragma unroll
    for (int n = 0; n < 16; ++n) {
        const int row = n * 16 + q;
        s1 += part1[row * 64 + c];
        s2 += part2[row * 64 + c];
    }
    r1[q][c] = s1; r2[q][c] = s2;
    __syncthreads();
    if (t < 64) {
        float S1 = 0.f, S2 = 0.f;
#pragma unroll
        for (int k = 0; k < 16; ++k) { S1 += r1[k][t]; S2 += r2[k][t]; }
        const float g = gamma[0];
        const float invN = 1.f / 16384.f;       // B*SY
        const float mean = S1 * invN;
        const float var  = S2 * invN - mean * mean;
        const float inv  = rsqrtf(g * g * var + 1e-5f);
        const float scale = g * inv * bn_w[t];
        sc[t] = scale;
        sh[t] = bn_b[t] - mean * scale;
    }
}

// ---------------------------------------------------------------------------
// K5: epilogue.  out[b][c][4jj..4jj+3] = x + O[b][c][jj]*scale[c] + shift[c]
// ---------------------------------------------------------------------------
__global__ __launch_bounds__(256) void k_out(
    const float* __restrict__ x, const float* __restrict__ Obuf,
    const float* __restrict__ sc, const float* __restrict__ sh,
    float* __restrict__ out)
{
    const int gid = blockIdx.x * 256 + threadIdx.x;   // 0 .. B*CX*SY-1
    const int c = (gid >> 11) & 63;
    const float o  = Obuf[gid];
    const float4 xv = reinterpret_cast<const float4*>(x)[gid];
    const float val = o * sc[c] + sh[c];
    float4 r;
    r.x = xv.x + val; r.y = xv.y + val; r.z = xv.z + val; r.w = xv.w + val;
    reinterpret_cast<float4*>(out)[gid] = r;
}

extern "C" void kernel_launch(void* const* d_in, const int* in_sizes, int n_in,
                              void* d_out, int out_size, void* d_ws, size_t ws_size,
                              hipStream_t stream)
{
    (void)in_sizes; (void)n_in; (void)out_size; (void)ws_size;
    const float* x  = (const float*)d_in[0];
    const float* y  = (const float*)d_in[1];
    const float* wq = (const float*)d_in[2];
    const float* bq = (const float*)d_in[3];
    const float* wk = (const float*)d_in[4];
    const float* bk = (const float*)d_in[5];
    const float* wv = (const float*)d_in[6];
    const float* bv = (const float*)d_in[7];
    const float* gm = (const float*)d_in[8];
    const float* bw = (const float*)d_in[9];
    const float* bb = (const float*)d_in[10];

    char* ws = (char*)d_ws;
    ushort_t* qT  = (ushort_t*)(ws + OFF_Q);
    ushort_t* kT  = (ushort_t*)(ws + OFF_K);
    ushort_t* vBp = (ushort_t*)(ws + OFF_V);
    float*    Ob  = (float*)(ws + OFF_O);
    float*    p1  = (float*)(ws + OFF_P1);
    float*    p2  = (float*)(ws + OFF_P2);
    float*    scp = (float*)(ws + OFF_SC);
    float*    shp = (float*)(ws + OFF_SH);

    k_prod<<<512, 1024, 0, stream>>>(y, wq, bq, wk, bk, qT, kT, x, wv, bv, vBp);
    k_attn<<<256, 1024, 0, stream>>>(qT, kT, vBp, Ob, p1, p2);
    k_bn  <<<1,   1024, 0, stream>>>(p1, p2, gm, bw, bb, scp, shp);
    k_out <<<4096, 256, 0, stream>>>(x, Ob, scp, shp, (float*)d_out);
}